// Round 7
// baseline (674.139 us; speedup 1.0000x reference)
//
#include <hip/hip_runtime.h>
#include <hip/hip_bf16.h>
#include <stdint.h>

typedef __attribute__((ext_vector_type(8))) short bf16x8;
typedef __attribute__((ext_vector_type(4))) float f32x4;

#define EPSB 1e-5f

// ---------------- workspace byte offsets ----------------
#define W0TE_B   0u          // [64][192] bf16, k = tap*64 + c
#define W1SB_B   24576u      // [128][64] bf16
#define W1E_B    40960u      // [2][128][192] bf16
#define W1R_B    139264u     // [128][64] bf16
#define PROJW_B  155648u     // [128][128] bf16
#define WS0F_B   188416u     // [64][4] f32
#define WR0F_B   189440u     // [64][4] f32
#define BS0F_B   190464u     // [64] f32
#define CB0F_B   190720u     // [64] f32
#define BS1F_B   190976u     // [128] f32
#define CB1F_B   191488u     // [128] f32
#define SPT_B    192000u     // [17][8] float2 {a, k-as-uint-bits}
#define SCRATCH_B 193536u
#define Y0_PERB  4456448ull  // 2048*17*64*2

__device__ __forceinline__ float bf2f(unsigned int u16v) {
    union { unsigned int i; float f; } v; v.i = u16v << 16; return v.f;
}
__device__ __forceinline__ unsigned short f2bf(float f) {
    unsigned int x = __float_as_uint(f);
    x = x + 0x7fffu + ((x >> 16) & 1u);   // RNE
    return (unsigned short)(x >> 16);
}
__device__ __forceinline__ unsigned pk2(float a, float b) {
    union { __hip_bfloat162 h; unsigned u; } v;
    v.h = __float22bfloat162_rn(make_float2(a, b));
    return v.u;
}
__device__ __forceinline__ int div17(int p) { return (p * 241) >> 12; }  // valid p<=255

struct PrepArgs {
    const float *sw0,*sb0,*sg0,*sbb0,*sm0,*sv0;
    const float *tw0,*tb0,*tg0,*tbb0,*tm0,*tv0;
    const float *rw0,*rb0,*rg0,*rbb0,*rm0,*rv0;
    const float *sw1,*sb1,*sg1,*sbb1,*sm1,*sv1;
    const float *tw1,*tb1,*tg1,*tbb1,*tm1,*tv1;
    const float *rw1,*rb1,*rg1,*rbb1,*rm1,*rv1;
    const float *projw;
    const float *adj;
    unsigned char* ws;
};

__global__ void prep_kernel(PrepArgs a) {
    const int g = blockIdx.x * 256 + threadIdx.x;
    unsigned short* W0TE  = (unsigned short*)(a.ws + W0TE_B);
    unsigned short* W1SBp = (unsigned short*)(a.ws + W1SB_B);
    unsigned short* W1Ep  = (unsigned short*)(a.ws + W1E_B);
    unsigned short* W1Rp  = (unsigned short*)(a.ws + W1R_B);
    unsigned short* PROJW = (unsigned short*)(a.ws + PROJW_B);
    float* WS0F = (float*)(a.ws + WS0F_B);
    float* WR0F = (float*)(a.ws + WR0F_B);
    float* BS0F = (float*)(a.ws + BS0F_B);
    float* CB0F = (float*)(a.ws + CB0F_B);
    float* BS1F = (float*)(a.ws + BS1F_B);
    float* CB1F = (float*)(a.ws + CB1F_B);
    float2* SPT = (float2*)(a.ws + SPT_B);

    if (g < 64) {
        int o = g;
        float scs = a.sg0[o] / sqrtf(a.sv0[o] + EPSB);
        BS0F[o] = scs * (a.sb0[o] - a.sm0[o]) + a.sbb0[o];
        for (int c = 0; c < 4; c++) WS0F[o*4+c] = (c < 3) ? scs * a.sw0[o*3+c] : 0.f;
        float tct = a.tg0[o] / sqrtf(a.tv0[o] + EPSB);
        float rcr = a.rg0[o] / sqrtf(a.rv0[o] + EPSB);
        CB0F[o] = tct * (a.tb0[o] - a.tm0[o]) + a.tbb0[o]
                + rcr * (a.rb0[o] - a.rm0[o]) + a.rbb0[o];
        for (int c = 0; c < 4; c++) WR0F[o*4+c] = (c < 3) ? rcr * a.rw0[o*3+c] : 0.f;
    } else if (g < 192) {
        int o = g - 64;
        float scs = a.sg1[o] / sqrtf(a.sv1[o] + EPSB);
        BS1F[o] = scs * (a.sb1[o] - a.sm1[o]) + a.sbb1[o];
        float tct = a.tg1[o] / sqrtf(a.tv1[o] + EPSB);
        float rcr = a.rg1[o] / sqrtf(a.rv1[o] + EPSB);
        CB1F[o] = tct * (a.tb1[o] - a.tm1[o]) + a.tbb1[o]
                + rcr * (a.rb1[o] - a.rm1[o]) + a.rbb1[o];
    } else if (g < 12480) {                   // W0TE: 64*192
        int idx = g - 192;
        int o = idx / 192, k = idx % 192, tap = k >> 6, c = k & 63;
        float tct = a.tg0[o] / sqrtf(a.tv0[o] + EPSB);
        W0TE[o*192 + k] = f2bf(tct * a.tw0[(o*64 + c)*3 + tap]);
    } else if (g < 20672) {                   // W1SB: 128*64
        int idx = g - 12480;
        int o = idx >> 6, c = idx & 63;
        float scs = a.sg1[o] / sqrtf(a.sv1[o] + EPSB);
        W1SBp[o*64 + c] = f2bf(scs * a.sw1[o*64 + c]);
    } else if (g < 69824) {                   // W1E: 2*128*192
        int idx = g - 20672;
        int h = idx / 24576, r = idx % 24576;
        int o = r / 192, k = r % 192, tap = k >> 6, c = (h << 6) + (k & 63);
        float tct = a.tg1[o] / sqrtf(a.tv1[o] + EPSB);
        W1Ep[(h*128 + o)*192 + k] = f2bf(tct * a.tw1[(o*128 + c)*3 + tap]);
    } else if (g < 78016) {                   // W1R: 128*64
        int idx = g - 69824;
        int o = idx >> 6, c = idx & 63;
        float rcr = a.rg1[o] / sqrtf(a.rv1[o] + EPSB);
        W1Rp[o*64 + c] = f2bf(rcr * a.rw1[o*64 + c]);
    } else if (g < 94400) {                   // PROJW: 128*128
        int idx = g - 78016;
        PROJW[idx] = f2bf(a.projw[idx]);
    } else if (g < 94417) {                   // sparse adj columns
        int j = g - 94400;
        int cnt = 0;
        for (int k = 0; k < 17; k++) {
            float v = a.adj[k*17 + j];
            if (v != 0.0f && cnt < 8) {
                SPT[j*8 + cnt] = make_float2(v, __uint_as_float((unsigned)k));
                cnt++;
            }
        }
        for (; cnt < 8; cnt++) SPT[j*8 + cnt] = make_float2(0.f, __uint_as_float(0u));
    }
}

// ---------------- block 0: 3 -> 64, T-tile 8; also emits yg = graphconv(y0) ----------------
__launch_bounds__(256, 3)
__global__ void b0_kernel(const float* __restrict__ x,
                          const unsigned char* __restrict__ ws,
                          unsigned short* __restrict__ Y0,
                          unsigned short* __restrict__ YG, int b0base) {
    __shared__ float xt[510];                 // [3][170]
    __shared__ float xg[510];
    __shared__ float2 sptA[136];              // offsets *4 (f32 rows)
    __shared__ float2 sptB[136];              // offsets *144 (bf16 [.][72] rows)
    __shared__ float Ws0s[256], Wr0s[256], bs0s[64], cb0s[64];
    __shared__ __align__(16) unsigned short s0[170*72];
    __shared__ __align__(16) unsigned short yst[136*72];

    const int tid = threadIdx.x;
    const int b_loc = blockIdx.x >> 8;
    const int b = b0base + b_loc;
    const int t0 = (blockIdx.x & 255) << 3;
    const int Pb = (t0 - 1) * 17;

    const int w = tid >> 6, l = tid & 63, lr = l & 15, lg = l >> 4;
    const int n = w*16 + lr;

    const unsigned short* W0TE = (const unsigned short*)(ws + W0TE_B);
    bf16x8 bfr[6];
    #pragma unroll
    for (int ks = 0; ks < 6; ks++)
        bfr[ks] = *(const bf16x8*)&W0TE[n*192 + ks*32 + lg*8];

    if (tid < 136) {
        float2 raw = ((const float2*)(ws + SPT_B))[tid];
        sptA[tid] = make_float2(raw.x, __uint_as_float(__float_as_uint(raw.y) * 4u));
        sptB[tid] = make_float2(raw.x, __uint_as_float(__float_as_uint(raw.y) * 144u));
    }
    Ws0s[tid] = ((const float*)(ws + WS0F_B))[tid];
    Wr0s[tid] = ((const float*)(ws + WR0F_B))[tid];
    if (tid < 64) {
        bs0s[tid] = ((const float*)(ws + BS0F_B))[tid];
        cb0s[tid] = ((const float*)(ws + CB0F_B))[tid];
    }
    #pragma unroll
    for (int it = 0; it < 2; it++) {          // x -> LDS
        int idx = tid + it*256;
        if (idx < 510) {
            int c = idx / 170, r = idx - c*170;
            int P = Pb + r;
            float v = 0.f;
            if (P >= 0 && P < 34816) v = x[(size_t)(b*3 + c)*34816 + P];
            xt[idx] = v;
        }
    }
    __syncthreads();
    #pragma unroll
    for (int it = 0; it < 2; it++) {          // sparse graph conv on x
        int idx = tid + it*256;
        if (idx < 510) {
            int c = idx / 170, r = idx - c*170;
            int j = r - 17*div17(r);
            const char* rowb = (const char*)&xt[c*170 + (r - j)];
            float acc = 0.f;
            #pragma unroll
            for (int i = 0; i < 8; i++) {
                float2 e = sptA[j*8 + i];
                acc += e.x * *(const float*)(rowb + __float_as_uint(e.y));
            }
            xg[idx] = acc;
        }
    }
    __syncthreads();
    #pragma unroll
    for (int it = 0; it < 11; it++) {         // s0 = relu(conv1x1(xg)), zero OOB rows
        int idx = tid + it*256;
        if (idx < 2720) {
            int r = idx >> 4, cg = idx & 15, o0 = cg*4;
            int P = Pb + r;
            uint2 pkv = make_uint2(0u, 0u);
            if (P >= 0 && P < 34816) {
                float a0 = xg[r], a1 = xg[170 + r], a2 = xg[340 + r];
                float v0 = fmaxf(bs0s[o0]   + Ws0s[(o0  )*4]*a0 + Ws0s[(o0  )*4+1]*a1 + Ws0s[(o0  )*4+2]*a2, 0.f);
                float v1 = fmaxf(bs0s[o0+1] + Ws0s[(o0+1)*4]*a0 + Ws0s[(o0+1)*4+1]*a1 + Ws0s[(o0+1)*4+2]*a2, 0.f);
                float v2 = fmaxf(bs0s[o0+2] + Ws0s[(o0+2)*4]*a0 + Ws0s[(o0+2)*4+1]*a1 + Ws0s[(o0+2)*4+2]*a2, 0.f);
                float v3 = fmaxf(bs0s[o0+3] + Ws0s[(o0+3)*4]*a0 + Ws0s[(o0+3)*4+1]*a1 + Ws0s[(o0+3)*4+2]*a2, 0.f);
                pkv.x = pk2(v0, v1); pkv.y = pk2(v2, v3);
            }
            *(uint2*)&s0[r*72 + o0] = pkv;
        }
    }
    __syncthreads();
    {   // tconv GEMM + residual -> yst
        const float wr0 = Wr0s[n*4], wr1 = Wr0s[n*4+1], wr2 = Wr0s[n*4+2];
        const float cbn = cb0s[n];
        for (int mb = 0; mb < 9; mb++) {
            const int ra = mb*16 + lr;
            f32x4 acc = {0.f, 0.f, 0.f, 0.f};
            #pragma unroll
            for (int ks = 0; ks < 6; ks++) {
                int row = ra + (ks >> 1)*17; if (row > 169) row = 169;
                const int c0 = ((ks & 1) << 5) + lg*8;
                acc = __builtin_amdgcn_mfma_f32_16x16x32_bf16(
                    *(const bf16x8*)&s0[row*72 + c0], bfr[ks], acc, 0, 0, 0);
            }
            const int mbase = mb*16 + lg*4;
            #pragma unroll
            for (int i = 0; i < 4; i++) {
                const int m = mbase + i;
                if (m < 136) {
                    float v = acc[i] + cbn + wr0*xt[m+17] + wr1*xt[170+m+17] + wr2*xt[340+m+17];
                    yst[m*72 + n] = f2bf(fmaxf(v, 0.f));
                }
            }
        }
    }
    __syncthreads();
    #pragma unroll
    for (int it = 0; it < 5; it++) {          // Y0 store (contiguous in m)
        int idx = tid + it*256;
        if (idx < 1088) {
            int m = idx >> 3, seg = idx & 7;
            uint4 v = *(const uint4*)&yst[m*72 + seg*8];
            *(uint4*)&Y0[((size_t)b_loc*34816 + t0*17 + m)*64 + seg*8] = v;
        }
    }
    #pragma unroll
    for (int it = 0; it < 9; it++) {          // yg = graphconv(yst), reg->global
        int idx = tid + it*256;
        if (idx < 2176) {
            int p = idx >> 4, cg = idx & 15;
            int j = p - 17*div17(p);
            const char* rowb = (const char*)yst + (p - j)*144 + cg*8;
            float a0=0.f, a1=0.f, a2=0.f, a3=0.f;
            #pragma unroll
            for (int i = 0; i < 8; i++) {
                float2 e = sptB[j*8 + i];
                uint2 u = *(const uint2*)(rowb + __float_as_uint(e.y));
                a0 += e.x * __uint_as_float(u.x << 16);
                a1 += e.x * __uint_as_float(u.x & 0xffff0000u);
                a2 += e.x * __uint_as_float(u.y << 16);
                a3 += e.x * __uint_as_float(u.y & 0xffff0000u);
            }
            uint2 o; o.x = pk2(a0, a1); o.y = pk2(a2, a3);
            *(uint2*)&YG[((size_t)b_loc*34816 + t0*17 + p)*64 + cg*4] = o;
        }
    }
}

// ---------------- block 1: 64 -> 128 + mean + fused projection ----------------
// tconv/resid: 4-way M-split (t-aligned, 34 rows/wave) x 2-way N-split (64 cols/wave)
__launch_bounds__(512, 2)
__global__ void b1_kernel(const unsigned char* __restrict__ ws,
                          const unsigned short* __restrict__ Y0,
                          const unsigned short* __restrict__ YG,
                          const float* __restrict__ projb,
                          float* __restrict__ outp, int b0base) {
    __shared__ __align__(16) unsigned short smem[36720];   // ybuf | ygbuf | s0buf, each [170][72]
    __shared__ __align__(16) unsigned short meansP[16*136];
    __shared__ float cb1s[128], bs1s[128];

    unsigned short* ybuf  = smem;
    unsigned short* ygbuf = smem + 12240;
    unsigned short* s0buf = smem + 24480;

    const int tid = threadIdx.x;
    const int b_loc = blockIdx.x >> 6;
    const int ck = blockIdx.x & 63;
    const int gb = b0base + b_loc;

    const unsigned short* W1SBp = (const unsigned short*)(ws + W1SB_B);
    const unsigned short* W1Ep  = (const unsigned short*)(ws + W1E_B);
    const unsigned short* W1Rp  = (const unsigned short*)(ws + W1R_B);
    const unsigned short* PROJW = (const unsigned short*)(ws + PROJW_B);

    const int w = tid >> 6, l = tid & 63, lr = l & 15, lg = l >> 4;
    const int wM = w & 3, wN = w >> 2;        // tconv/resid roles
    const int rM = wM * 34;                   // wave's first output row (t-aligned)
    const int sNt = w & 3, sMh = w >> 2;      // s1 roles (unchanged)
    const int nloc_s = sNt*16 + lr;

    if (tid < 128) {
        cb1s[tid] = ((const float*)(ws + CB1F_B))[tid];
        bs1s[tid] = ((const float*)(ws + BS1F_B))[tid];
    }

    uint4 pf[5];
    auto PF = [&](int t0n) {
        const int Pbn = t0n*17 - 17;
        #pragma unroll
        for (int s = 0; s < 5; s++) {
            int idx = tid + s*512;
            uint4 v = make_uint4(0u,0u,0u,0u);
            if (idx < 1360) {                 // yg halo rows 0..169
                int p = idx >> 3, seg = idx & 7;
                int P = Pbn + p;
                if (P >= 0 && P < 34816)
                    v = *(const uint4*)&YG[((size_t)b_loc*34816 + P)*64 + seg*8];
            } else if (idx < 2448) {          // y0 center rows 0..135
                int p = (idx - 1360) >> 3, seg = (idx - 1360) & 7;
                v = *(const uint4*)&Y0[((size_t)b_loc*34816 + t0n*17 + p)*64 + seg*8];
            }
            pf[s] = v;
        }
    };
    PF(ck << 5);

    for (int tt = 0; tt < 4; tt++) {
        const int t0 = (ck << 5) + (tt << 3);
        const int Pb = (t0 - 1) * 17;
        const bool edge = (Pb < 0) || (Pb + 169 >= 34816);

        // ---- P0: commit prefetched tile ----
        #pragma unroll
        for (int s = 0; s < 5; s++) {
            int idx = tid + s*512;
            if (idx < 1360) {
                int p = idx >> 3, seg = idx & 7;
                *(uint4*)&ygbuf[p*72 + seg*8] = pf[s];
            } else if (idx < 2448) {
                int p = (idx - 1360) >> 3, seg = (idx - 1360) & 7;
                *(uint4*)&ybuf[(17 + p)*72 + seg*8] = pf[s];
            }
        }
        __syncthreads();

        // ---- P1: next-tile prefetch + residual GEMM (M/N-split) + s1 h0 -> s0buf ----
        if (tt < 3) PF(t0 + 8);

        f32x4 tacc[3][4];
        #pragma unroll
        for (int mbL = 0; mbL < 3; mbL++)
            #pragma unroll
            for (int nb = 0; nb < 4; nb++) tacc[mbL][nb] = (f32x4){0.f,0.f,0.f,0.f};

        {   // residual: A rows 17+rM+mbL*16+lr (<=166), K=64
            bf16x8 ra_[3][2];
            #pragma unroll
            for (int mbL = 0; mbL < 3; mbL++)
                #pragma unroll
                for (int kf = 0; kf < 2; kf++)
                    ra_[mbL][kf] = *(const bf16x8*)&ybuf[(17 + rM + mbL*16 + lr)*72 + kf*32 + lg*8];
            #pragma unroll
            for (int nb = 0; nb < 4; nb++) {
                const int n = wN*64 + nb*16 + lr;
                bf16x8 rb0 = *(const bf16x8*)&W1Rp[n*64 + lg*8];
                bf16x8 rb1 = *(const bf16x8*)&W1Rp[n*64 + 32 + lg*8];
                #pragma unroll
                for (int mbL = 0; mbL < 3; mbL++) {
                    tacc[mbL][nb] = __builtin_amdgcn_mfma_f32_16x16x32_bf16(ra_[mbL][0], rb0, tacc[mbL][nb], 0, 0, 0);
                    tacc[mbL][nb] = __builtin_amdgcn_mfma_f32_16x16x32_bf16(ra_[mbL][1], rb1, tacc[mbL][nb], 0, 0, 0);
                }
            }
        }
        {   // s1 h0 (old N-split roles)
            bf16x8 sbA = *(const bf16x8*)&W1SBp[(nloc_s)*64 + lg*8];
            bf16x8 sbB = *(const bf16x8*)&W1SBp[(nloc_s)*64 + 32 + lg*8];
            const float bias = bs1s[nloc_s];
            const int mbS = sMh ? 6 : 0, mbE = sMh ? 11 : 6;
            if (!edge) {
                for (int mb = mbS; mb < mbE; mb++) {
                    int ra = mb*16 + lr; if (ra > 169) ra = 169;
                    f32x4 sa = {0.f, 0.f, 0.f, 0.f};
                    sa = __builtin_amdgcn_mfma_f32_16x16x32_bf16(*(const bf16x8*)&ygbuf[ra*72 + lg*8],      sbA, sa, 0, 0, 0);
                    sa = __builtin_amdgcn_mfma_f32_16x16x32_bf16(*(const bf16x8*)&ygbuf[ra*72 + 32 + lg*8], sbB, sa, 0, 0, 0);
                    const int mbase = mb*16 + lg*4;
                    #pragma unroll
                    for (int i = 0; i < 4; i++) {
                        int m = mbase + i;
                        if (m < 170) s0buf[m*72 + nloc_s] = f2bf(fmaxf(sa[i] + bias, 0.f));
                    }
                }
            } else {
                for (int mb = mbS; mb < mbE; mb++) {
                    int ra = mb*16 + lr; if (ra > 169) ra = 169;
                    f32x4 sa = {0.f, 0.f, 0.f, 0.f};
                    sa = __builtin_amdgcn_mfma_f32_16x16x32_bf16(*(const bf16x8*)&ygbuf[ra*72 + lg*8],      sbA, sa, 0, 0, 0);
                    sa = __builtin_amdgcn_mfma_f32_16x16x32_bf16(*(const bf16x8*)&ygbuf[ra*72 + 32 + lg*8], sbB, sa, 0, 0, 0);
                    const int mbase = mb*16 + lg*4;
                    #pragma unroll
                    for (int i = 0; i < 4; i++) {
                        int m = mbase + i;
                        if (m < 170) {
                            int P = Pb + m;
                            float v = (P >= 0 && P < 34816) ? fmaxf(sa[i] + bias, 0.f) : 0.f;
                            s0buf[m*72 + nloc_s] = f2bf(v);
                        }
                    }
                }
            }
        }
        __syncthreads();

        // ---- P2: tconv h0 (s0buf, M/N-split) + s1 h1 -> ybuf ----
        {
            bf16x8 af[3][6];
            #pragma unroll
            for (int mbL = 0; mbL < 3; mbL++)
                #pragma unroll
                for (int ks = 0; ks < 6; ks++) {
                    int row = rM + mbL*16 + lr + (ks >> 1)*17; if (row > 169) row = 169;
                    af[mbL][ks] = *(const bf16x8*)&s0buf[row*72 + ((ks & 1) << 5) + lg*8];
                }
            __builtin_amdgcn_s_setprio(1);
            #pragma unroll
            for (int nb = 0; nb < 4; nb++) {
                const int n = wN*64 + nb*16 + lr;
                bf16x8 bf_[6];
                #pragma unroll
                for (int ks = 0; ks < 6; ks++)
                    bf_[ks] = *(const bf16x8*)&W1Ep[n*192 + ks*32 + lg*8];     // h=0
                #pragma unroll
                for (int mbL = 0; mbL < 3; mbL++)
                    #pragma unroll
                    for (int ks = 0; ks < 6; ks++)
                        tacc[mbL][nb] = __builtin_amdgcn_mfma_f32_16x16x32_bf16(af[mbL][ks], bf_[ks], tacc[mbL][nb], 0, 0, 0);
            }
            __builtin_amdgcn_s_setprio(0);
        }
        {   // s1 h1
            bf16x8 sbA = *(const bf16x8*)&W1SBp[(64 + nloc_s)*64 + lg*8];
            bf16x8 sbB = *(const bf16x8*)&W1SBp[(64 + nloc_s)*64 + 32 + lg*8];
            const float bias = bs1s[64 + nloc_s];
            const int mbS = sMh ? 6 : 0, mbE = sMh ? 11 : 6;
            if (!edge) {
                for (int mb = mbS; mb < mbE; mb++) {
                    int ra = mb*16 + lr; if (ra > 169) ra = 169;
                    f32x4 sa = {0.f, 0.f, 0.f, 0.f};
                    sa = __builtin_amdgcn_mfma_f32_16x16x32_bf16(*(const bf16x8*)&ygbuf[ra*72 + lg*8],      sbA, sa, 0, 0, 0);
                    sa = __builtin_amdgcn_mfma_f32_16x16x32_bf16(*(const bf16x8*)&ygbuf[ra*72 + 32 + lg*8], sbB, sa, 0, 0, 0);
                    const int mbase = mb*16 + lg*4;
                    #pragma unroll
                    for (int i = 0; i < 4; i++) {
                        int m = mbase + i;
                        if (m < 170) ybuf[m*72 + nloc_s] = f2bf(fmaxf(sa[i] + bias, 0.f));
                    }
                }
            } else {
                for (int mb = mbS; mb < mbE; mb++) {
                    int ra = mb*16 + lr; if (ra > 169) ra = 169;
                    f32x4 sa = {0.f, 0.f, 0.f, 0.f};
                    sa = __builtin_amdgcn_mfma_f32_16x16x32_bf16(*(const bf16x8*)&ygbuf[ra*72 + lg*8],      sbA, sa, 0, 0, 0);
                    sa = __builtin_amdgcn_mfma_f32_16x16x32_bf16(*(const bf16x8*)&ygbuf[ra*72 + 32 + lg*8], sbB, sa, 0, 0, 0);
                    const int mbase = mb*16 + lg*4;
                    #pragma unroll
                    for (int i = 0; i < 4; i++) {
                        int m = mbase + i;
                        if (m < 170) {
                            int P = Pb + m;
                            float v = (P >= 0 && P < 34816) ? fmaxf(sa[i] + bias, 0.f) : 0.f;
                            ybuf[m*72 + nloc_s] = f2bf(v);
                        }
                    }
                }
            }
        }
        __syncthreads();

        // ---- P3: tconv h1 (ybuf, M/N-split) + wave-local mean over J -> meansP ----
        {
            bf16x8 af[3][6];
            #pragma unroll
            for (int mbL = 0; mbL < 3; mbL++)
                #pragma unroll
                for (int ks = 0; ks < 6; ks++) {
                    int row = rM + mbL*16 + lr + (ks >> 1)*17; if (row > 169) row = 169;
                    af[mbL][ks] = *(const bf16x8*)&ybuf[row*72 + ((ks & 1) << 5) + lg*8];
                }
            __builtin_amdgcn_s_setprio(1);
            #pragma unroll
            for (int nb = 0; nb < 4; nb++) {
                const int n = wN*64 + nb*16 + lr;
                bf16x8 bf_[6];
                #pragma unroll
                for (int ks = 0; ks < 6; ks++)
                    bf_[ks] = *(const bf16x8*)&W1Ep[(128 + n)*192 + ks*32 + lg*8]; // h=1
                #pragma unroll
                for (int mbL = 0; mbL < 3; mbL++)
                    #pragma unroll
                    for (int ks = 0; ks < 6; ks++)
                        tacc[mbL][nb] = __builtin_amdgcn_mfma_f32_16x16x32_bf16(af[mbL][ks], bf_[ks], tacc[mbL][nb], 0, 0, 0);
            }
            __builtin_amdgcn_s_setprio(0);
        }
        {   // mean over J: wave covers t = 2*wM + {0,1}; local rows: t0 -> [0,16], t1 -> [17,33]
            const int nbase = wN*64 + lr;
            const int mrow = (tt & 1) * 8 + wM*2;
            #pragma unroll
            for (int nb = 0; nb < 4; nb++) {
                const float cbv = cb1s[nbase + nb*16];
                float v00 = fmaxf(tacc[0][nb][0] + cbv, 0.f);
                float v01 = fmaxf(tacc[0][nb][1] + cbv, 0.f);
                float v02 = fmaxf(tacc[0][nb][2] + cbv, 0.f);
                float v03 = fmaxf(tacc[0][nb][3] + cbv, 0.f);
                float v10 = fmaxf(tacc[1][nb][0] + cbv, 0.f);
                float v11 = fmaxf(tacc[1][nb][1] + cbv, 0.f);
                float v12 = fmaxf(tacc[1][nb][2] + cbv, 0.f);
                float v13 = fmaxf(tacc[1][nb][3] + cbv, 0.f);
                float v20 = fmaxf(tacc[2][nb][0] + cbv, 0.f);
                float v21 = fmaxf(tacc[2][nb][1] + cbv, 0.f);
                float s0 = v00 + v01 + v02 + v03;       // rows lg*4+0..3 (all in [0,15])
                float s1v = v10 + v11 + v12 + v13;      // rows 16+lg*4+0..3
                float bnd  = (lg == 0) ? v10 : 0.f;     // row 16 -> t0
                float tail = (lg == 0) ? (v20 + v21) : 0.f;  // rows 32,33 -> t1
                float t0s = s0 + bnd;
                float t1s = s1v - bnd + tail;
                t0s += __shfl_xor(t0s, 16, 64); t0s += __shfl_xor(t0s, 32, 64);
                t1s += __shfl_xor(t1s, 16, 64); t1s += __shfl_xor(t1s, 32, 64);
                if (lg == nb) {
                    meansP[(mrow    )*136 + nbase + nb*16] = f2bf(t0s * (1.f/17.f));
                    meansP[(mrow + 1)*136 + nbase + nb*16] = f2bf(t1s * (1.f/17.f));
                }
            }
        }
        __syncthreads();

        // ---- P4 (every 2nd tile): projection of 16 t-rows -> d_out ----
        if (tt & 1) {
            const int et = w;                 // e-block 0..7
            bf16x8 pw[4];
            #pragma unroll
            for (int kf = 0; kf < 4; kf++)
                pw[kf] = *(const bf16x8*)&PROJW[(et*16 + lr)*128 + kf*32 + lg*8];
            f32x4 pa = {0.f, 0.f, 0.f, 0.f};
            #pragma unroll
            for (int kf = 0; kf < 4; kf++)
                pa = __builtin_amdgcn_mfma_f32_16x16x32_bf16(
                    *(const bf16x8*)&meansP[lr*136 + kf*32 + lg*8], pw[kf], pa, 0, 0, 0);
            const float pb = projb[et*16 + lr];
            const int tbase = ck*32 + (tt - 1)*8;
            #pragma unroll
            for (int i = 0; i < 4; i++) {
                const int m = lg*4 + i;
                outp[((size_t)gb*2048 + tbase + m)*128 + et*16 + lr] = pa[i] + pb;
            }
        }
    }
}

extern "C" void kernel_launch(void* const* d_in, const int* in_sizes, int n_in,
                              void* d_out, int out_size, void* d_ws, size_t ws_size,
                              hipStream_t stream) {
    const float* x     = (const float*)d_in[0];
    const float* adj   = (const float*)d_in[1];
    const float* projb = (const float*)d_in[39];
    unsigned char* ws  = (unsigned char*)d_ws;

    PrepArgs pa;
    pa.sw0 = (const float*)d_in[2];  pa.sb0  = (const float*)d_in[3];
    pa.sg0 = (const float*)d_in[4];  pa.sbb0 = (const float*)d_in[5];
    pa.sm0 = (const float*)d_in[6];  pa.sv0  = (const float*)d_in[7];
    pa.tw0 = (const float*)d_in[8];  pa.tb0  = (const float*)d_in[9];
    pa.tg0 = (const float*)d_in[10]; pa.tbb0 = (const float*)d_in[11];
    pa.tm0 = (const float*)d_in[12]; pa.tv0  = (const float*)d_in[13];
    pa.rw0 = (const float*)d_in[14]; pa.rb0  = (const float*)d_in[15];
    pa.rg0 = (const float*)d_in[16]; pa.rbb0 = (const float*)d_in[17];
    pa.rm0 = (const float*)d_in[18]; pa.rv0  = (const float*)d_in[19];
    pa.sw1 = (const float*)d_in[20]; pa.sb1  = (const float*)d_in[21];
    pa.sg1 = (const float*)d_in[22]; pa.sbb1 = (const float*)d_in[23];
    pa.sm1 = (const float*)d_in[24]; pa.sv1  = (const float*)d_in[25];
    pa.tw1 = (const float*)d_in[26]; pa.tb1  = (const float*)d_in[27];
    pa.tg1 = (const float*)d_in[28]; pa.tbb1 = (const float*)d_in[29];
    pa.tm1 = (const float*)d_in[30]; pa.tv1  = (const float*)d_in[31];
    pa.rw1 = (const float*)d_in[32]; pa.rb1  = (const float*)d_in[33];
    pa.rg1 = (const float*)d_in[34]; pa.rbb1 = (const float*)d_in[35];
    pa.rm1 = (const float*)d_in[36]; pa.rv1  = (const float*)d_in[37];
    pa.projw = (const float*)d_in[38];
    pa.adj = adj;
    pa.ws = ws;

    prep_kernel<<<dim3(369), dim3(256), 0, stream>>>(pa);

    // per-batch scratch: Y0 + YG
    const size_t perb = 2ull * Y0_PERB;
    int chunk = 16;
    while (chunk > 1 && (size_t)SCRATCH_B + (size_t)chunk * perb > ws_size) chunk >>= 1;

    unsigned short* Y0p = (unsigned short*)(ws + SCRATCH_B);
    unsigned short* YGp = (unsigned short*)((unsigned char*)Y0p + (size_t)chunk * Y0_PERB);

    for (int cb = 0; cb < 16; cb += chunk) {
        b0_kernel<<<dim3(chunk * 256), dim3(256), 0, stream>>>(x, ws, Y0p, YGp, cb);
        b1_kernel<<<dim3(chunk * 64), dim3(512), 0, stream>>>(ws, Y0p, YGp, projb, (float*)d_out, cb);
    }
}